// Round 1
// baseline (288.265 us; speedup 1.0000x reference)
//
#include <hip/hip_runtime.h>

// Problem constants (from reference)
#define BB 16
#define TT 2000
#define FF 481
#define NDF_ 96
#define ORDER_ 5

// spec  : (16, 1, 2000, 481, 2) f32   row stride = 962 floats
// coefs : (16, 2000, 5, 96, 2) f32    per-(b,t) stride = 960 floats
// alpha : (16, 2000, 1) f32
// out   : same shape as spec
//
// out[b,t,f<96] = a * (sum_k x[b, t-4+k, f] * c[b,t,k,f]) + (1-a) * x[b,t,f]
//   (complex multiply, zero-padded for t-4+k < 0)
// out[b,t,f>=96] = spec[b,t,f]

__global__ __launch_bounds__(256) void df_op_kernel(
    const float* __restrict__ spec,
    const float* __restrict__ coefs,
    const float* __restrict__ alpha,
    float* __restrict__ out)
{
    const int bt = blockIdx.x;            // 0 .. 16*2000-1
    const int b  = bt / TT;
    const int t  = bt - b * TT;
    const int tid = threadIdx.x;

    const long row = (long)bt * (FF * 2); // float offset of this (b,t) row
    const float a = alpha[bt];
    const float oma = 1.0f - a;

    if (tid < NDF_) {
        const int f = tid;
        float acc_re = 0.0f, acc_im = 0.0f;
        const float2* cbase = (const float2*)(coefs + (long)bt * (ORDER_ * NDF_ * 2) + f * 2);
        #pragma unroll
        for (int k = 0; k < ORDER_; ++k) {
            const int tk = t - (ORDER_ - 1) + k;
            float2 x = make_float2(0.0f, 0.0f);
            if (tk >= 0) {
                x = *(const float2*)(spec + ((long)b * TT + tk) * (FF * 2) + f * 2);
            }
            const float2 c = cbase[k * NDF_];   // stride NDF_ float2's between taps
            acc_re += x.x * c.x - x.y * c.y;
            acc_im += x.y * c.x + x.x * c.y;
        }
        const float2 s = *(const float2*)(spec + row + f * 2);
        float2 o;
        o.x = acc_re * a + s.x * oma;
        o.y = acc_im * a + s.y * oma;
        *(float2*)(out + row + f * 2) = o;
    }

    // Copy bins [96, 481): 385 float2 elements, 8-byte aligned (row stride 962
    // floats is even, offset 192 is even).
    const float2* src = (const float2*)(spec + row + NDF_ * 2);
    float2*       dst = (float2*)(out + row + NDF_ * 2);
    for (int i = tid; i < (FF - NDF_); i += 256) {
        dst[i] = src[i];
    }
}

extern "C" void kernel_launch(void* const* d_in, const int* in_sizes, int n_in,
                              void* d_out, int out_size, void* d_ws, size_t ws_size,
                              hipStream_t stream) {
    const float* spec  = (const float*)d_in[0];
    const float* coefs = (const float*)d_in[1];
    const float* alpha = (const float*)d_in[2];
    float* out = (float*)d_out;

    dim3 grid(BB * TT);
    dim3 block(256);
    df_op_kernel<<<grid, block, 0, stream>>>(spec, coefs, alpha, out);
}